// Round 1
// baseline (764.852 us; speedup 1.0000x reference)
//
#include <hip/hip_runtime.h>
#include <hip/hip_bf16.h>
#include <math.h>

// Problem constants (fixed by the reference): B=32768, K=32, D=128.
#define B_ROWS 32768
#define KNBR 32
#define DDIM 128

// ws layout (floats):
//   [0,128)            v_ego = W_msg^T a[:128]
//   [128,256)          v_nbr = W_msg^T a[128:]
//   [256, 256+16384)   WmT[d*128+e] = W_msg[e*128+d]
//   [16640, 33024)     WsT[d*128+e] = W_self[e*128+d]
#define WS_VEGO 0
#define WS_VNBR 128
#define WS_WMT  256
#define WS_WST  (256 + 128*128)

__global__ __launch_bounds__(256) void prep_kernel(
    const float* __restrict__ W_msg, const float* __restrict__ W_attn,
    const float* __restrict__ W_self, float* __restrict__ ws) {
    int t = threadIdx.x;
    int gid = blockIdx.x * 256 + t;
    if (gid < 128 * 128) {
        int e = gid >> 7, d = gid & 127;
        ws[WS_WMT + d * 128 + e] = W_msg[e * 128 + d];
        ws[WS_WST + d * 128 + e] = W_self[e * 128 + d];
    }
    if (blockIdx.x == 0 && t < 128) {
        float ve = 0.f, vn = 0.f;
        for (int e = 0; e < 128; ++e) {
            float w = W_msg[e * 128 + t];
            ve += W_attn[e] * w;
            vn += W_attn[128 + e] * w;
        }
        ws[WS_VEGO + t] = ve;
        ws[WS_VNBR + t] = vn;
    }
}

// One block per row b. 256 threads = 4 waves.
__global__ __launch_bounds__(256) void attn_kernel(
    const float* __restrict__ h_ego, const float* __restrict__ h_nei,
    const int* __restrict__ nbr_mask, const float* __restrict__ ws,
    float* __restrict__ hbar_out) {
    __shared__ float hn[KNBR * DDIM];   // 16 KB
    __shared__ float he[DDIM];
    __shared__ float sve[DDIM];
    __shared__ float svn[DDIM];
    __shared__ float s_raw[KNBR];
    __shared__ float s_attn[KNBR];
    __shared__ float s_ego;

    int t = threadIdx.x;
    long b = blockIdx.x;

    // Stage h_nei row tile: 4096 floats = 1024 float4, 4 per thread, coalesced.
    const float4* src = (const float4*)(h_nei + b * (KNBR * DDIM));
    float4* dst = (float4*)hn;
#pragma unroll
    for (int i = 0; i < 4; ++i) dst[i * 256 + t] = src[i * 256 + t];
    if (t < 32) {
        ((float4*)he)[t] = ((const float4*)(h_ego + b * DDIM))[t];
    } else if (t < 64) {
        ((float4*)sve)[t - 32] = ((const float4*)(ws + WS_VEGO))[t - 32];
    } else if (t < 96) {
        ((float4*)svn)[t - 64] = ((const float4*)(ws + WS_VNBR))[t - 64];
    }
    __syncthreads();

    int w = t >> 6, l = t & 63;

    // Ego logit contribution (wave 0).
    if (w == 0) {
        float p = he[l] * sve[l] + he[l + 64] * sve[l + 64];
#pragma unroll
        for (int s = 32; s; s >>= 1) p += __shfl_xor(p, s, 64);
        if (l == 0) s_ego = p;
    }
    // Neighbour dot products: each wave handles 8 of the 32 neighbours.
#pragma unroll
    for (int j = 0; j < 8; ++j) {
        int k = w * 8 + j;
        const float* row = hn + k * DDIM;
        float p = row[l] * svn[l] + row[l + 64] * svn[l + 64];
#pragma unroll
        for (int s = 32; s; s >>= 1) p += __shfl_xor(p, s, 64);
        if (l == 0) s_raw[k] = p;
    }
    __syncthreads();

    // Softmax over K=32 in wave 0 (lanes >=32 carry -inf / 0).
    if (w == 0) {
        float logit = -INFINITY;
        bool valid = false;
        if (l < KNBR) {
            float x = s_raw[l] + s_ego;
            x = x > 0.f ? x : 0.2f * x;              // leaky_relu(0.2)
            valid = nbr_mask[b * KNBR + l] > 0;
            logit = valid ? x : -INFINITY;
        }
        float m = logit;
#pragma unroll
        for (int s = 32; s; s >>= 1) m = fmaxf(m, __shfl_xor(m, s, 64));
        float e = valid ? __expf(logit - m) : 0.f;
        float ssum = e;
#pragma unroll
        for (int s = 32; s; s >>= 1) ssum += __shfl_xor(ssum, s, 64);
        if (l < KNBR) s_attn[l] = (ssum > 0.f) ? e / ssum : 0.f;
    }
    __syncthreads();

    // hbar[d] = sum_k attn[k] * hn[k][d]; write into d_out (consumed by out_kernel).
    if (t < DDIM) {
        float acc = 0.f;
#pragma unroll
        for (int k = 0; k < KNBR; ++k) acc += s_attn[k] * hn[k * DDIM + t];
        hbar_out[b * DDIM + t] = acc;
    }
}

// 32 rows per block; out = tanh(hbar @ WmT + h_ego @ WsT + b_self).
// Reads hbar from d_out, overwrites d_out in place (rows disjoint per block).
__global__ __launch_bounds__(256) void out_kernel(
    const float* __restrict__ h_ego, const float* __restrict__ ws,
    const float* __restrict__ b_self, float* __restrict__ out) {
    __shared__ float xh[32 * DDIM];  // hbar tile, 16 KB
    __shared__ float xe[32 * DDIM];  // h_ego tile, 16 KB

    int t = threadIdx.x;
    long rbase = (long)blockIdx.x * 32;

    const float4* srcH = (const float4*)(out + rbase * DDIM);
    const float4* srcE = (const float4*)(h_ego + rbase * DDIM);
#pragma unroll
    for (int i = 0; i < 4; ++i) {
        ((float4*)xh)[i * 256 + t] = srcH[i * 256 + t];
        ((float4*)xe)[i * 256 + t] = srcE[i * 256 + t];
    }
    __syncthreads();

    const float4* WmT = (const float4*)(ws + WS_WMT);
    const float4* WsT = (const float4*)(ws + WS_WST);
    int tc = t & 31;   // col group -> e = tc*4 .. tc*4+3
    int tr = t >> 5;   // row group -> r = tr*4 .. tr*4+3

    float acc[4][4] = {{0.f}};
    for (int d = 0; d < 128; ++d) {
        float4 wm = WmT[d * 32 + tc];
        float4 wsv = WsT[d * 32 + tc];
#pragma unroll
        for (int r = 0; r < 4; ++r) {
            float a = xh[(tr * 4 + r) * DDIM + d];
            float bb = xe[(tr * 4 + r) * DDIM + d];
            acc[r][0] += a * wm.x + bb * wsv.x;
            acc[r][1] += a * wm.y + bb * wsv.y;
            acc[r][2] += a * wm.z + bb * wsv.z;
            acc[r][3] += a * wm.w + bb * wsv.w;
        }
    }

    float4 bv = ((const float4*)b_self)[tc];
#pragma unroll
    for (int r = 0; r < 4; ++r) {
        float4 o;
        o.x = tanhf(acc[r][0] + bv.x);
        o.y = tanhf(acc[r][1] + bv.y);
        o.z = tanhf(acc[r][2] + bv.z);
        o.w = tanhf(acc[r][3] + bv.w);
        ((float4*)(out + (rbase + tr * 4 + r) * DDIM))[tc] = o;
    }
}

extern "C" void kernel_launch(void* const* d_in, const int* in_sizes, int n_in,
                              void* d_out, int out_size, void* d_ws, size_t ws_size,
                              hipStream_t stream) {
    const float* h_ego   = (const float*)d_in[0];
    const float* h_nei   = (const float*)d_in[1];
    const int*   nbr_mask= (const int*)d_in[2];
    const float* W_msg   = (const float*)d_in[3];
    const float* W_attn  = (const float*)d_in[4];
    const float* W_self  = (const float*)d_in[5];
    const float* b_self  = (const float*)d_in[6];
    float* out = (float*)d_out;
    float* ws  = (float*)d_ws;

    prep_kernel<<<64, 256, 0, stream>>>(W_msg, W_attn, W_self, ws);
    attn_kernel<<<B_ROWS, 256, 0, stream>>>(h_ego, h_nei, nbr_mask, ws, out);
    out_kernel<<<B_ROWS / 32, 256, 0, stream>>>(h_ego, ws, b_self, out);
}

// Round 2
// 755.922 us; speedup vs baseline: 1.0118x; 1.0118x over previous
//
#include <hip/hip_runtime.h>
#include <hip/hip_bf16.h>
#include <math.h>

// Problem constants (fixed by the reference): B=32768, K=32, D=128.
#define B_ROWS 32768
#define KNBR 32
#define DDIM 128

// ws layout (floats):
//   [0,128)            v_ego = W_msg^T a[:128]
//   [128,256)          v_nbr = W_msg^T a[128:]
//   [256, 256+16384)   WmT[d*128+e] = W_msg[e*128+d]
//   [16640, 33024)     WsT[d*128+e] = W_self[e*128+d]
#define WS_VEGO 0
#define WS_VNBR 128
#define WS_WMT  256
#define WS_WST  (256 + 128*128)

__global__ __launch_bounds__(256) void prep_kernel(
    const float* __restrict__ W_msg, const float* __restrict__ W_attn,
    const float* __restrict__ W_self, float* __restrict__ ws) {
    int t = threadIdx.x;
    int gid = blockIdx.x * 256 + t;
    if (gid < 128 * 128) {
        int e = gid >> 7, d = gid & 127;
        ws[WS_WMT + d * 128 + e] = W_msg[e * 128 + d];
        ws[WS_WST + d * 128 + e] = W_self[e * 128 + d];
    }
    if (blockIdx.x == 0 && t < 128) {
        float ve = 0.f, vn = 0.f;
        for (int e = 0; e < 128; ++e) {
            float w = W_msg[e * 128 + t];
            ve += W_attn[e] * w;
            vn += W_attn[128 + e] * w;
        }
        ws[WS_VEGO + t] = ve;
        ws[WS_VNBR + t] = vn;
    }
}

// Wave-per-row: 256 threads = 4 waves = 4 rows per block, 8192 blocks.
// No LDS, no __syncthreads. Each lane keeps d={2l,2l+1} of all 32 neighbour
// rows in registers (64 VGPRs), so h_nei is read exactly once from HBM.
__global__ __launch_bounds__(256) void attn_kernel(
    const float* __restrict__ h_ego, const float* __restrict__ h_nei,
    const int* __restrict__ nbr_mask, const float* __restrict__ ws,
    float* __restrict__ hbar_out) {
    int t = threadIdx.x;
    int w = t >> 6, l = t & 63;
    long b = (long)blockIdx.x * 4 + w;

    // Per-lane slices of the folded attention vectors and h_ego.
    float2 vn2 = ((const float2*)(ws + WS_VNBR))[l];
    float2 ve2 = ((const float2*)(ws + WS_VEGO))[l];
    float2 he2 = ((const float2*)(h_ego + b * DDIM))[l];

    // Stage the full neighbour tile into registers: 32 independent dwordx2.
    const float2* row = (const float2*)(h_nei + b * (KNBR * DDIM));
    float2 hreg[KNBR];
#pragma unroll
    for (int k = 0; k < KNBR; ++k) hreg[k] = row[k * 64 + l];

    // Validity bitmask (wave-uniform): bit k = nbr_mask[b][k] > 0.
    int mv = nbr_mask[b * KNBR + (l & 31)];
    unsigned long long bal = __ballot((l < KNBR) && (mv > 0));
    unsigned vmask = (unsigned)bal;

    // Ego logit contribution (butterfly -> replicated in all lanes).
    float pe = he2.x * ve2.x + he2.y * ve2.y;
#pragma unroll
    for (int s = 32; s; s >>= 1) pe += __shfl_xor(pe, s, 64);

    // Neighbour logits: butterfly per k; every lane ends with all 32 logits,
    // so softmax is lane-replicated (zero further communication).
    float e[KNBR];
    float m = -INFINITY;
#pragma unroll
    for (int k = 0; k < KNBR; ++k) {
        float p = hreg[k].x * vn2.x + hreg[k].y * vn2.y;
#pragma unroll
        for (int s = 32; s; s >>= 1) p += __shfl_xor(p, s, 64);
        p += pe;
        p = p > 0.f ? p : 0.2f * p;                 // leaky_relu(0.2)
        p = ((vmask >> k) & 1u) ? p : -INFINITY;
        e[k] = p;
        m = fmaxf(m, p);
    }
    float ssum = 0.f;
#pragma unroll
    for (int k = 0; k < KNBR; ++k) {
        float ev = ((vmask >> k) & 1u) ? __expf(e[k] - m) : 0.f;
        e[k] = ev;
        ssum += ev;
    }
    float inv = ssum > 0.f ? 1.f / ssum : 0.f;      // all-masked row -> hbar = 0

    // hbar slice: pure register FMA.
    float2 acc = make_float2(0.f, 0.f);
#pragma unroll
    for (int k = 0; k < KNBR; ++k) {
        acc.x += e[k] * hreg[k].x;
        acc.y += e[k] * hreg[k].y;
    }
    acc.x *= inv;
    acc.y *= inv;
    ((float2*)(hbar_out + b * DDIM))[l] = acc;
}

// 32 rows per block; out = tanh(hbar @ WmT + h_ego @ WsT + b_self).
// Reads hbar from d_out, overwrites d_out in place (rows disjoint per block).
__global__ __launch_bounds__(256) void out_kernel(
    const float* __restrict__ h_ego, const float* __restrict__ ws,
    const float* __restrict__ b_self, float* __restrict__ out) {
    __shared__ float xh[32 * DDIM];  // hbar tile, 16 KB
    __shared__ float xe[32 * DDIM];  // h_ego tile, 16 KB

    int t = threadIdx.x;
    long rbase = (long)blockIdx.x * 32;

    const float4* srcH = (const float4*)(out + rbase * DDIM);
    const float4* srcE = (const float4*)(h_ego + rbase * DDIM);
#pragma unroll
    for (int i = 0; i < 4; ++i) {
        ((float4*)xh)[i * 256 + t] = srcH[i * 256 + t];
        ((float4*)xe)[i * 256 + t] = srcE[i * 256 + t];
    }
    __syncthreads();

    const float4* WmT = (const float4*)(ws + WS_WMT);
    const float4* WsT = (const float4*)(ws + WS_WST);
    int tc = t & 31;   // col group -> e = tc*4 .. tc*4+3
    int tr = t >> 5;   // row group -> r = tr*4 .. tr*4+3

    float acc[4][4] = {{0.f}};
    for (int d = 0; d < 128; ++d) {
        float4 wm = WmT[d * 32 + tc];
        float4 wsv = WsT[d * 32 + tc];
#pragma unroll
        for (int r = 0; r < 4; ++r) {
            float a = xh[(tr * 4 + r) * DDIM + d];
            float bb = xe[(tr * 4 + r) * DDIM + d];
            acc[r][0] += a * wm.x + bb * wsv.x;
            acc[r][1] += a * wm.y + bb * wsv.y;
            acc[r][2] += a * wm.z + bb * wsv.z;
            acc[r][3] += a * wm.w + bb * wsv.w;
        }
    }

    float4 bv = ((const float4*)b_self)[tc];
#pragma unroll
    for (int r = 0; r < 4; ++r) {
        float4 o;
        o.x = tanhf(acc[r][0] + bv.x);
        o.y = tanhf(acc[r][1] + bv.y);
        o.z = tanhf(acc[r][2] + bv.z);
        o.w = tanhf(acc[r][3] + bv.w);
        ((float4*)(out + (rbase + tr * 4 + r) * DDIM))[tc] = o;
    }
}

extern "C" void kernel_launch(void* const* d_in, const int* in_sizes, int n_in,
                              void* d_out, int out_size, void* d_ws, size_t ws_size,
                              hipStream_t stream) {
    const float* h_ego   = (const float*)d_in[0];
    const float* h_nei   = (const float*)d_in[1];
    const int*   nbr_mask= (const int*)d_in[2];
    const float* W_msg   = (const float*)d_in[3];
    const float* W_attn  = (const float*)d_in[4];
    const float* W_self  = (const float*)d_in[5];
    const float* b_self  = (const float*)d_in[6];
    float* out = (float*)d_out;
    float* ws  = (float*)d_ws;

    prep_kernel<<<64, 256, 0, stream>>>(W_msg, W_attn, W_self, ws);
    attn_kernel<<<B_ROWS / 4, 256, 0, stream>>>(h_ego, h_nei, nbr_mask, ws, out);
    out_kernel<<<B_ROWS / 32, 256, 0, stream>>>(h_ego, ws, b_self, out);
}